// Round 1
// baseline (1094.877 us; speedup 1.0000x reference)
//
#include <hip/hip_runtime.h>

#define N_NODES 50000
#define N_EDGES 800000
#define IN_F 256
#define OUT_F 64
#define HEADS 4
#define HF 256  // HEADS*OUT_F
#define NEG_SLOPE 0.2f

// ---- monotone float<->uint encoding for atomicMax on floats (any sign) ----
__device__ __forceinline__ unsigned encf(float f) {
  unsigned u = __float_as_uint(f);
  return (u & 0x80000000u) ? ~u : (u | 0x80000000u);
}
__device__ __forceinline__ float decf(unsigned k) {
  unsigned u = (k & 0x80000000u) ? (k & 0x7FFFFFFFu) : ~k;
  return __uint_as_float(u);
}

// ---- Kernel 1: h[n, hd*64+f] = sum_k x[n,k] * W[hd,k,f] ----
// 64x64 tile per block (blockIdx.x = node tile, blockIdx.y = head),
// BK=32, 4x4 register tile per thread, LDS-staged operands.
__global__ __launch_bounds__(256) void k_gemm(const float* __restrict__ x,
                                              const float* __restrict__ W,
                                              float* __restrict__ h) {
  __shared__ __align__(16) float xs[32][68];  // [k][m], stride 68 (16B-aligned rows)
  __shared__ __align__(16) float ws[32][64];  // [k][f]
  const int t = threadIdx.x;
  const int n0 = blockIdx.x * 64;
  const int hd = blockIdx.y;
  const int f0 = (t & 15) * 4;   // 0..60
  const int m0 = (t >> 4) * 4;   // 0..60
  const float* Wh = W + hd * (IN_F * OUT_F);

  float acc[4][4];
#pragma unroll
  for (int i = 0; i < 4; i++)
#pragma unroll
    for (int j = 0; j < 4; j++) acc[i][j] = 0.f;

  for (int k0 = 0; k0 < IN_F; k0 += 32) {
    // stage x tile (transposed into [k][m])
#pragma unroll
    for (int qq = 0; qq < 2; qq++) {
      int q = t + qq * 256;          // 0..511
      int row = q >> 3, c4 = q & 7;  // row: m 0..63, c4: k-quad 0..7
      int gr = n0 + row;
      gr = gr < N_NODES ? gr : (N_NODES - 1);
      float4 v = *(const float4*)(x + (size_t)gr * IN_F + k0 + c4 * 4);
      xs[c4 * 4 + 0][row] = v.x;
      xs[c4 * 4 + 1][row] = v.y;
      xs[c4 * 4 + 2][row] = v.z;
      xs[c4 * 4 + 3][row] = v.w;
    }
    // stage W tile (natural [k][f])
#pragma unroll
    for (int qq = 0; qq < 2; qq++) {
      int q = t + qq * 256;
      int kk = q >> 4, o4 = q & 15;
      *(float4*)(&ws[kk][o4 * 4]) = *(const float4*)(Wh + (size_t)(k0 + kk) * OUT_F + o4 * 4);
    }
    __syncthreads();
#pragma unroll
    for (int kk = 0; kk < 32; kk++) {
      float4 a = *(const float4*)(&xs[kk][m0]);
      float4 b = *(const float4*)(&ws[kk][f0]);
      acc[0][0] += a.x * b.x; acc[0][1] += a.x * b.y; acc[0][2] += a.x * b.z; acc[0][3] += a.x * b.w;
      acc[1][0] += a.y * b.x; acc[1][1] += a.y * b.y; acc[1][2] += a.y * b.z; acc[1][3] += a.y * b.w;
      acc[2][0] += a.z * b.x; acc[2][1] += a.z * b.y; acc[2][2] += a.z * b.z; acc[2][3] += a.z * b.w;
      acc[3][0] += a.w * b.x; acc[3][1] += a.w * b.y; acc[3][2] += a.w * b.z; acc[3][3] += a.w * b.w;
    }
    __syncthreads();
  }
#pragma unroll
  for (int i = 0; i < 4; i++) {
    int m = n0 + m0 + i;
    if (m < N_NODES) {
      float4 v = make_float4(acc[i][0], acc[i][1], acc[i][2], acc[i][3]);
      *(float4*)(h + (size_t)m * HF + hd * OUT_F + f0) = v;
    }
  }
}

// ---- Kernel 2: attn_src[hd,n] = h[n,hd*64+:]·a_src[hd], same for dst ----
// one block per node; wave w handles head w (64 lanes = 64 feats).
__global__ __launch_bounds__(256) void k_attn(const float* __restrict__ h,
                                              const float* __restrict__ a_src,
                                              const float* __restrict__ a_dst,
                                              float* __restrict__ as,
                                              float* __restrict__ ad) {
  int n = blockIdx.x;
  int t = threadIdx.x;
  int hd = t >> 6, lane = t & 63;
  float hv = h[(size_t)n * HF + t];
  float s = hv * a_src[hd * OUT_F + lane];
  float d = hv * a_dst[hd * OUT_F + lane];
#pragma unroll
  for (int off = 32; off > 0; off >>= 1) {
    s += __shfl_down(s, off);
    d += __shfl_down(d, off);
  }
  if (lane == 0) {
    as[hd * N_NODES + n] = s;
    ad[hd * N_NODES + n] = d;
  }
}

// ---- Kernel 3: global max of e over [H,E] ----
__global__ __launch_bounds__(256) void k_edge_max(const int* __restrict__ src,
                                                  const int* __restrict__ dst,
                                                  const float* __restrict__ ew,
                                                  const float* __restrict__ as,
                                                  const float* __restrict__ ad,
                                                  unsigned* __restrict__ gmax) {
  int e = blockIdx.x * 256 + threadIdx.x;
  int s = src[e], d = dst[e];
  float w = ew[e];
  float m = -3.4e38f;
#pragma unroll
  for (int hd = 0; hd < HEADS; hd++) {
    float v = as[hd * N_NODES + s] + ad[hd * N_NODES + d];
    v = v >= 0.f ? v : NEG_SLOPE * v;
    v *= w;
    m = fmaxf(m, v);
  }
#pragma unroll
  for (int off = 32; off > 0; off >>= 1) m = fmaxf(m, __shfl_down(m, off));
  __shared__ float red[4];
  int wave = threadIdx.x >> 6, lane = threadIdx.x & 63;
  if (lane == 0) red[wave] = m;
  __syncthreads();
  if (threadIdx.x == 0) {
    float mm = fmaxf(fmaxf(red[0], red[1]), fmaxf(red[2], red[3]));
    atomicMax(gmax, encf(mm));
  }
}

// ---- Kernel 4: e_exp = exp(e - gmax); denom[hd,dst] += e_exp ----
__global__ __launch_bounds__(256) void k_expden(const int* __restrict__ src,
                                                const int* __restrict__ dst,
                                                const float* __restrict__ ew,
                                                const float* __restrict__ as,
                                                const float* __restrict__ ad,
                                                const unsigned* __restrict__ gmax,
                                                float* __restrict__ eexp,
                                                float* __restrict__ denom) {
  int e = blockIdx.x * 256 + threadIdx.x;
  int s = src[e], d = dst[e];
  float w = ew[e];
  float gm = decf(*gmax);
#pragma unroll
  for (int hd = 0; hd < HEADS; hd++) {
    float v = as[hd * N_NODES + s] + ad[hd * N_NODES + d];
    v = v >= 0.f ? v : NEG_SLOPE * v;
    float ex = __expf(v * w - gm);
    eexp[hd * N_EDGES + e] = ex;
    atomicAdd(denom + hd * N_NODES + d, ex);
  }
}

// ---- Kernel 5: alpha = e_exp / (denom[dst] + 1e-10), in place ----
__global__ __launch_bounds__(256) void k_alpha(const int* __restrict__ dst,
                                               const float* __restrict__ denom,
                                               float* __restrict__ eexp) {
  int e = blockIdx.x * 256 + threadIdx.x;
  int d = dst[e];
#pragma unroll
  for (int hd = 0; hd < HEADS; hd++) {
    float dn = denom[hd * N_NODES + d] + 1e-10f;
    eexp[hd * N_EDGES + e] = eexp[hd * N_EDGES + e] / dn;
  }
}

// ---- Kernel 6: out[dst, f] += alpha[hd,e] * h[src, f]  (f = hd*64+o) ----
__global__ __launch_bounds__(256) void k_agg(const int* __restrict__ src,
                                             const int* __restrict__ dst,
                                             const float* __restrict__ h,
                                             const float* __restrict__ alpha,
                                             float* __restrict__ out) {
  int e = blockIdx.x;
  int t = threadIdx.x;
  int hd = t >> 6;
  int s = src[e], d = dst[e];
  float al = alpha[hd * N_EDGES + e];
  float v = h[(size_t)s * HF + t] * al;
  atomicAdd(out + (size_t)d * HF + t, v);
}

extern "C" void kernel_launch(void* const* d_in, const int* in_sizes, int n_in,
                              void* d_out, int out_size, void* d_ws, size_t ws_size,
                              hipStream_t stream) {
  const float* x     = (const float*)d_in[0];
  const int*   ei    = (const int*)d_in[1];
  const float* ew    = (const float*)d_in[2];
  const float* W     = (const float*)d_in[3];
  const float* a_src = (const float*)d_in[4];
  const float* a_dst = (const float*)d_in[5];
  float* out = (float*)d_out;

  // workspace layout (floats): h | attn_src | attn_dst | denom | eexp | gmax
  float* h     = (float*)d_ws;
  float* as    = h + (size_t)N_NODES * HF;              // 12.8M
  float* ad    = as + (size_t)HEADS * N_NODES;          // +200K
  float* denom = ad + (size_t)HEADS * N_NODES;          // +200K
  float* eexp  = denom + (size_t)HEADS * N_NODES;       // +200K
  unsigned* gmax = (unsigned*)(eexp + (size_t)HEADS * N_EDGES);  // +3.2M

  const int* src = ei;
  const int* dst = ei + N_EDGES;

  hipMemsetAsync(out, 0, (size_t)out_size * sizeof(float), stream);
  hipMemsetAsync(denom, 0, (size_t)HEADS * N_NODES * sizeof(float), stream);
  hipMemsetAsync(gmax, 0, sizeof(unsigned), stream);  // 0 < encf(-inf): valid identity

  dim3 g1((N_NODES + 63) / 64, HEADS);
  k_gemm<<<g1, 256, 0, stream>>>(x, W, h);
  k_attn<<<N_NODES, 256, 0, stream>>>(h, a_src, a_dst, as, ad);
  k_edge_max<<<N_EDGES / 256, 256, 0, stream>>>(src, dst, ew, as, ad, gmax);
  k_expden<<<N_EDGES / 256, 256, 0, stream>>>(src, dst, ew, as, ad, gmax, eexp, denom);
  k_alpha<<<N_EDGES / 256, 256, 0, stream>>>(dst, denom, eexp);
  k_agg<<<N_EDGES, 256, 0, stream>>>(src, dst, h, eexp, out);
}

// Round 2
// 580.748 us; speedup vs baseline: 1.8853x; 1.8853x over previous
//
#include <hip/hip_runtime.h>

#define N_NODES 50000
#define N_EDGES 800000
#define IN_F 256
#define OUT_F 64
#define HEADS 4
#define HF 256  // HEADS*OUT_F
#define NEG_SLOPE 0.2f

// ---- monotone float<->uint encoding for atomicMax on floats ----
__device__ __forceinline__ unsigned encf(float f) {
  unsigned u = __float_as_uint(f);
  return (u & 0x80000000u) ? ~u : (u | 0x80000000u);
}
__device__ __forceinline__ float decf(unsigned k) {
  unsigned u = (k & 0x80000000u) ? (k & 0x7FFFFFFFu) : ~k;
  return __uint_as_float(u);
}

// ---- Kernel 1: h = x @ W per head, fused attn-logit epilogue ----
// 64x64 tile, BK=32, 4x4 reg tile. Epilogue: per-row dot with a_src/a_dst,
// shfl-reduced over the 16 f-groups (width=16 segments within a wave).
__global__ __launch_bounds__(256) void k_gemm(const float* __restrict__ x,
                                              const float* __restrict__ W,
                                              const float* __restrict__ a_src,
                                              const float* __restrict__ a_dst,
                                              float* __restrict__ h,
                                              float* __restrict__ as_out,
                                              float* __restrict__ ad_out) {
  __shared__ __align__(16) float xs[32][68];
  __shared__ __align__(16) float ws[32][64];
  const int t = threadIdx.x;
  const int n0 = blockIdx.x * 64;
  const int hd = blockIdx.y;
  const int f0 = (t & 15) * 4;
  const int m0 = (t >> 4) * 4;
  const float* Wh = W + hd * (IN_F * OUT_F);

  float acc[4][4];
#pragma unroll
  for (int i = 0; i < 4; i++)
#pragma unroll
    for (int j = 0; j < 4; j++) acc[i][j] = 0.f;

  for (int k0 = 0; k0 < IN_F; k0 += 32) {
#pragma unroll
    for (int qq = 0; qq < 2; qq++) {
      int q = t + qq * 256;
      int row = q >> 3, c4 = q & 7;
      int gr = n0 + row;
      gr = gr < N_NODES ? gr : (N_NODES - 1);
      float4 v = *(const float4*)(x + (size_t)gr * IN_F + k0 + c4 * 4);
      xs[c4 * 4 + 0][row] = v.x;
      xs[c4 * 4 + 1][row] = v.y;
      xs[c4 * 4 + 2][row] = v.z;
      xs[c4 * 4 + 3][row] = v.w;
    }
#pragma unroll
    for (int qq = 0; qq < 2; qq++) {
      int q = t + qq * 256;
      int kk = q >> 4, o4 = q & 15;
      *(float4*)(&ws[kk][o4 * 4]) = *(const float4*)(Wh + (size_t)(k0 + kk) * OUT_F + o4 * 4);
    }
    __syncthreads();
#pragma unroll
    for (int kk = 0; kk < 32; kk++) {
      float4 a = *(const float4*)(&xs[kk][m0]);
      float4 b = *(const float4*)(&ws[kk][f0]);
      acc[0][0] += a.x * b.x; acc[0][1] += a.x * b.y; acc[0][2] += a.x * b.z; acc[0][3] += a.x * b.w;
      acc[1][0] += a.y * b.x; acc[1][1] += a.y * b.y; acc[1][2] += a.y * b.z; acc[1][3] += a.y * b.w;
      acc[2][0] += a.z * b.x; acc[2][1] += a.z * b.y; acc[2][2] += a.z * b.z; acc[2][3] += a.z * b.w;
      acc[3][0] += a.w * b.x; acc[3][1] += a.w * b.y; acc[3][2] += a.w * b.z; acc[3][3] += a.w * b.w;
    }
    __syncthreads();
  }
#pragma unroll
  for (int i = 0; i < 4; i++) {
    int m = n0 + m0 + i;
    if (m < N_NODES) {
      float4 v = make_float4(acc[i][0], acc[i][1], acc[i][2], acc[i][3]);
      *(float4*)(h + (size_t)m * HF + hd * OUT_F + f0) = v;
    }
  }
  // fused attention-logit epilogue: as[hd,n] = h[n]·a_src[hd], ad likewise
  const float4 asv = *(const float4*)(a_src + hd * OUT_F + f0);
  const float4 adv = *(const float4*)(a_dst + hd * OUT_F + f0);
  float ps[4], pd[4];
#pragma unroll
  for (int i = 0; i < 4; i++) {
    ps[i] = acc[i][0] * asv.x + acc[i][1] * asv.y + acc[i][2] * asv.z + acc[i][3] * asv.w;
    pd[i] = acc[i][0] * adv.x + acc[i][1] * adv.y + acc[i][2] * adv.z + acc[i][3] * adv.w;
  }
#pragma unroll
  for (int off = 8; off > 0; off >>= 1) {
#pragma unroll
    for (int i = 0; i < 4; i++) {
      ps[i] += __shfl_down(ps[i], off, 16);
      pd[i] += __shfl_down(pd[i], off, 16);
    }
  }
  if ((t & 15) == 0) {
#pragma unroll
    for (int i = 0; i < 4; i++) {
      int m = n0 + m0 + i;
      if (m < N_NODES) {
        as_out[hd * N_NODES + m] = ps[i];
        ad_out[hd * N_NODES + m] = pd[i];
      }
    }
  }
}

// ---- Kernel 2: global max of e over [H,E], fused dst-degree histogram ----
__global__ __launch_bounds__(256) void k_edge_max(const int* __restrict__ src,
                                                  const int* __restrict__ dst,
                                                  const float* __restrict__ ew,
                                                  const float* __restrict__ as,
                                                  const float* __restrict__ ad,
                                                  unsigned* __restrict__ gmax,
                                                  int* __restrict__ deg) {
  int e = blockIdx.x * 256 + threadIdx.x;
  int s = src[e], d = dst[e];
  float w = ew[e];
  atomicAdd(deg + d, 1);
  float m = -3.4e38f;
#pragma unroll
  for (int hd = 0; hd < HEADS; hd++) {
    float v = as[hd * N_NODES + s] + ad[hd * N_NODES + d];
    v = v >= 0.f ? v : NEG_SLOPE * v;
    v *= w;
    m = fmaxf(m, v);
  }
#pragma unroll
  for (int off = 32; off > 0; off >>= 1) m = fmaxf(m, __shfl_down(m, off));
  __shared__ float red[4];
  int wave = threadIdx.x >> 6, lane = threadIdx.x & 63;
  if (lane == 0) red[wave] = m;
  __syncthreads();
  if (threadIdx.x == 0) {
    float mm = fmaxf(fmaxf(red[0], red[1]), fmaxf(red[2], red[3]));
    atomicMax(gmax, encf(mm));
  }
}

// ---- Scan kernels: exclusive prefix sum of deg[50000] ----
__global__ __launch_bounds__(256) void k_scan1(const int* __restrict__ deg,
                                               int* __restrict__ excl,
                                               int* __restrict__ bsum) {
  int i = blockIdx.x * 256 + threadIdx.x;
  int orig = (i < N_NODES) ? deg[i] : 0;
  int v = orig;
  int lane = threadIdx.x & 63, wave = threadIdx.x >> 6;
#pragma unroll
  for (int off = 1; off < 64; off <<= 1) {
    int u = __shfl_up(v, off);
    if (lane >= off) v += u;
  }
  __shared__ int wsum[4];
  if (lane == 63) wsum[wave] = v;
  __syncthreads();
  int base = 0;
  for (int w = 0; w < wave; w++) base += wsum[w];
  int incl = v + base;
  if (i < N_NODES) excl[i] = incl - orig;
  if (threadIdx.x == 255) bsum[blockIdx.x] = incl;
}

__global__ __launch_bounds__(256) void k_scan2(int* __restrict__ bsum, int nb) {
  int t = threadIdx.x;
  int orig = (t < nb) ? bsum[t] : 0;
  int v = orig;
  int lane = t & 63, wave = t >> 6;
#pragma unroll
  for (int off = 1; off < 64; off <<= 1) {
    int u = __shfl_up(v, off);
    if (lane >= off) v += u;
  }
  __shared__ int wsum[4];
  if (lane == 63) wsum[wave] = v;
  __syncthreads();
  int base = 0;
  for (int w = 0; w < wave; w++) base += wsum[w];
  if (t < nb) bsum[t] = v + base - orig;
}

__global__ __launch_bounds__(256) void k_scan3(const int* __restrict__ excl,
                                               const int* __restrict__ bsum,
                                               int* __restrict__ row_start,
                                               int* __restrict__ cursor) {
  int i = blockIdx.x * 256 + threadIdx.x;
  if (i < N_NODES) {
    int rs = excl[i] + bsum[blockIdx.x];
    row_start[i] = rs;
    cursor[i] = rs;
  }
}

// ---- Kernel 3: e_exp + denom + scatter into dst-sorted CSR slots ----
__global__ __launch_bounds__(256) void k_expden(const int* __restrict__ src,
                                                const int* __restrict__ dst,
                                                const float* __restrict__ ew,
                                                const float* __restrict__ as,
                                                const float* __restrict__ ad,
                                                const unsigned* __restrict__ gmax,
                                                float* __restrict__ denom,
                                                int* __restrict__ cursor,
                                                int* __restrict__ sorted_src,
                                                float* __restrict__ esort) {
  int e = blockIdx.x * 256 + threadIdx.x;
  int s = src[e], d = dst[e];
  float w = ew[e];
  float gm = decf(*gmax);
  float ex[HEADS];
#pragma unroll
  for (int hd = 0; hd < HEADS; hd++) {
    float v = as[hd * N_NODES + s] + ad[hd * N_NODES + d];
    v = v >= 0.f ? v : NEG_SLOPE * v;
    ex[hd] = __expf(v * w - gm);
    atomicAdd(denom + hd * N_NODES + d, ex[hd]);
  }
  int pos = atomicAdd(cursor + d, 1);
  sorted_src[pos] = s;
  *(float4*)(esort + (size_t)pos * 4) = make_float4(ex[0], ex[1], ex[2], ex[3]);
}

// ---- Kernel 4: atomic-free aggregation. One node per block. ----
// out[d, hd*64+o] = (sum_j esort[j][hd] * h[src_j, hd*64+o]) / (denom+eps)
__global__ __launch_bounds__(256) void k_agg(const int* __restrict__ row_start,
                                             const int* __restrict__ deg,
                                             const int* __restrict__ sorted_src,
                                             const float* __restrict__ esort,
                                             const float* __restrict__ h,
                                             const float* __restrict__ denom,
                                             float* __restrict__ out) {
  int d = blockIdx.x;
  int t = threadIdx.x;
  int hd = t >> 6;
  int rs = row_start[d];
  int dg = deg[d];
  float acc = 0.f;
  int j = 0;
  for (; j + 1 < dg; j += 2) {
    int s0 = sorted_src[rs + j];
    int s1 = sorted_src[rs + j + 1];
    float a0 = esort[(size_t)(rs + j) * 4 + hd];
    float a1 = esort[(size_t)(rs + j + 1) * 4 + hd];
    float h0 = h[(size_t)s0 * HF + t];
    float h1 = h[(size_t)s1 * HF + t];
    acc += a0 * h0 + a1 * h1;
  }
  if (j < dg) {
    int s0 = sorted_src[rs + j];
    float a0 = esort[(size_t)(rs + j) * 4 + hd];
    acc += a0 * h[(size_t)s0 * HF + t];
  }
  float dn = denom[hd * N_NODES + d] + 1e-10f;
  out[(size_t)d * HF + t] = acc / dn;
}

extern "C" void kernel_launch(void* const* d_in, const int* in_sizes, int n_in,
                              void* d_out, int out_size, void* d_ws, size_t ws_size,
                              hipStream_t stream) {
  const float* x     = (const float*)d_in[0];
  const int*   ei    = (const int*)d_in[1];
  const float* ew    = (const float*)d_in[2];
  const float* W     = (const float*)d_in[3];
  const float* a_src = (const float*)d_in[4];
  const float* a_dst = (const float*)d_in[5];
  float* out = (float*)d_out;

  // workspace layout (16B-aligned first): h | esort | as | ad | denom |
  //   deg | excl | row_start | cursor | sorted_src | bsum | gmax
  float* h     = (float*)d_ws;                             // 12.8M f
  float* esort = h + (size_t)N_NODES * HF;                 // 3.2M f
  float* as    = esort + (size_t)N_EDGES * 4;              // 200K f
  float* ad    = as + (size_t)HEADS * N_NODES;             // 200K f
  float* denom = ad + (size_t)HEADS * N_NODES;             // 200K f
  int* deg        = (int*)(denom + (size_t)HEADS * N_NODES);  // 50K i
  int* excl       = deg + N_NODES;
  int* row_start  = excl + N_NODES;
  int* cursor     = row_start + N_NODES;
  int* sorted_src = cursor + N_NODES;                      // 800K i
  int* bsum       = sorted_src + N_EDGES;                  // 256 i
  unsigned* gmax  = (unsigned*)(bsum + 256);

  const int* src = ei;
  const int* dst = ei + N_EDGES;
  const int NB = (N_NODES + 255) / 256;  // 196

  hipMemsetAsync(denom, 0, (size_t)HEADS * N_NODES * sizeof(float), stream);
  hipMemsetAsync(deg, 0, (size_t)N_NODES * sizeof(int), stream);
  hipMemsetAsync(gmax, 0, sizeof(unsigned), stream);

  dim3 g1((N_NODES + 63) / 64, HEADS);
  k_gemm<<<g1, 256, 0, stream>>>(x, W, a_src, a_dst, h, as, ad);
  k_edge_max<<<N_EDGES / 256, 256, 0, stream>>>(src, dst, ew, as, ad, gmax, deg);
  k_scan1<<<NB, 256, 0, stream>>>(deg, excl, bsum);
  k_scan2<<<1, 256, 0, stream>>>(bsum, NB);
  k_scan3<<<NB, 256, 0, stream>>>(excl, bsum, row_start, cursor);
  k_expden<<<N_EDGES / 256, 256, 0, stream>>>(src, dst, ew, as, ad, gmax,
                                              denom, cursor, sorted_src, esort);
  k_agg<<<N_NODES, 256, 0, stream>>>(row_start, deg, sorted_src, esort, h, denom, out);
}

// Round 3
// 448.718 us; speedup vs baseline: 2.4400x; 1.2942x over previous
//
#include <hip/hip_runtime.h>

#define N_NODES 50000
#define N_EDGES 800000
#define IN_F 256
#define OUT_F 64
#define HEADS 4
#define HF 256  // HEADS*OUT_F
#define NEG_SLOPE 0.2f

// ---- monotone float<->uint encoding for atomicMax on floats ----
__device__ __forceinline__ unsigned encf(float f) {
  unsigned u = __float_as_uint(f);
  return (u & 0x80000000u) ? ~u : (u | 0x80000000u);
}
__device__ __forceinline__ float decf(unsigned k) {
  unsigned u = (k & 0x80000000u) ? (k & 0x7FFFFFFFu) : ~k;
  return __uint_as_float(u);
}

// ---- Kernel 1: h = x @ W per head, fused attn-logit epilogue ----
__global__ __launch_bounds__(256) void k_gemm(const float* __restrict__ x,
                                              const float* __restrict__ W,
                                              const float* __restrict__ a_src,
                                              const float* __restrict__ a_dst,
                                              float* __restrict__ h,
                                              float* __restrict__ as_out,
                                              float* __restrict__ ad_out) {
  __shared__ __align__(16) float xs[32][68];
  __shared__ __align__(16) float ws[32][64];
  const int t = threadIdx.x;
  const int n0 = blockIdx.x * 64;
  const int hd = blockIdx.y;
  const int f0 = (t & 15) * 4;
  const int m0 = (t >> 4) * 4;
  const float* Wh = W + hd * (IN_F * OUT_F);

  float acc[4][4];
#pragma unroll
  for (int i = 0; i < 4; i++)
#pragma unroll
    for (int j = 0; j < 4; j++) acc[i][j] = 0.f;

  for (int k0 = 0; k0 < IN_F; k0 += 32) {
#pragma unroll
    for (int qq = 0; qq < 2; qq++) {
      int q = t + qq * 256;
      int row = q >> 3, c4 = q & 7;
      int gr = n0 + row;
      gr = gr < N_NODES ? gr : (N_NODES - 1);
      float4 v = *(const float4*)(x + (size_t)gr * IN_F + k0 + c4 * 4);
      xs[c4 * 4 + 0][row] = v.x;
      xs[c4 * 4 + 1][row] = v.y;
      xs[c4 * 4 + 2][row] = v.z;
      xs[c4 * 4 + 3][row] = v.w;
    }
#pragma unroll
    for (int qq = 0; qq < 2; qq++) {
      int q = t + qq * 256;
      int kk = q >> 4, o4 = q & 15;
      *(float4*)(&ws[kk][o4 * 4]) = *(const float4*)(Wh + (size_t)(k0 + kk) * OUT_F + o4 * 4);
    }
    __syncthreads();
#pragma unroll
    for (int kk = 0; kk < 32; kk++) {
      float4 a = *(const float4*)(&xs[kk][m0]);
      float4 b = *(const float4*)(&ws[kk][f0]);
      acc[0][0] += a.x * b.x; acc[0][1] += a.x * b.y; acc[0][2] += a.x * b.z; acc[0][3] += a.x * b.w;
      acc[1][0] += a.y * b.x; acc[1][1] += a.y * b.y; acc[1][2] += a.y * b.z; acc[1][3] += a.y * b.w;
      acc[2][0] += a.z * b.x; acc[2][1] += a.z * b.y; acc[2][2] += a.z * b.z; acc[2][3] += a.z * b.w;
      acc[3][0] += a.w * b.x; acc[3][1] += a.w * b.y; acc[3][2] += a.w * b.z; acc[3][3] += a.w * b.w;
    }
    __syncthreads();
  }
#pragma unroll
  for (int i = 0; i < 4; i++) {
    int m = n0 + m0 + i;
    if (m < N_NODES) {
      float4 v = make_float4(acc[i][0], acc[i][1], acc[i][2], acc[i][3]);
      *(float4*)(h + (size_t)m * HF + hd * OUT_F + f0) = v;
    }
  }
  // fused attention-logit epilogue
  const float4 asv = *(const float4*)(a_src + hd * OUT_F + f0);
  const float4 adv = *(const float4*)(a_dst + hd * OUT_F + f0);
  float ps[4], pd[4];
#pragma unroll
  for (int i = 0; i < 4; i++) {
    ps[i] = acc[i][0] * asv.x + acc[i][1] * asv.y + acc[i][2] * asv.z + acc[i][3] * asv.w;
    pd[i] = acc[i][0] * adv.x + acc[i][1] * adv.y + acc[i][2] * adv.z + acc[i][3] * adv.w;
  }
#pragma unroll
  for (int off = 8; off > 0; off >>= 1) {
#pragma unroll
    for (int i = 0; i < 4; i++) {
      ps[i] += __shfl_down(ps[i], off, 16);
      pd[i] += __shfl_down(pd[i], off, 16);
    }
  }
  if ((t & 15) == 0) {
#pragma unroll
    for (int i = 0; i < 4; i++) {
      int m = n0 + m0 + i;
      if (m < N_NODES) {
        as_out[hd * N_NODES + m] = ps[i];
        ad_out[hd * N_NODES + m] = pd[i];
      }
    }
  }
}

// ---- Kernel 2: global max of e over [H,E] + dst-degree histogram ----
__global__ __launch_bounds__(256) void k_edge_max(const int* __restrict__ src,
                                                  const int* __restrict__ dst,
                                                  const float* __restrict__ ew,
                                                  const float* __restrict__ as,
                                                  const float* __restrict__ ad,
                                                  unsigned* __restrict__ gmax,
                                                  int* __restrict__ deg) {
  int e = blockIdx.x * 256 + threadIdx.x;
  int s = src[e], d = dst[e];
  float w = ew[e];
  atomicAdd(deg + d, 1);
  float m = -3.4e38f;
#pragma unroll
  for (int hd = 0; hd < HEADS; hd++) {
    float v = as[hd * N_NODES + s] + ad[hd * N_NODES + d];
    v = v >= 0.f ? v : NEG_SLOPE * v;
    v *= w;
    m = fmaxf(m, v);
  }
#pragma unroll
  for (int off = 32; off > 0; off >>= 1) m = fmaxf(m, __shfl_down(m, off));
  __shared__ float red[4];
  int wave = threadIdx.x >> 6, lane = threadIdx.x & 63;
  if (lane == 0) red[wave] = m;
  __syncthreads();
  if (threadIdx.x == 0) {
    float mm = fmaxf(fmaxf(red[0], red[1]), fmaxf(red[2], red[3]));
    atomicMax(gmax, encf(mm));
  }
}

// ---- Scan kernels: exclusive prefix sum of deg[50000] ----
__global__ __launch_bounds__(256) void k_scan1(const int* __restrict__ deg,
                                               int* __restrict__ excl,
                                               int* __restrict__ bsum) {
  int i = blockIdx.x * 256 + threadIdx.x;
  int orig = (i < N_NODES) ? deg[i] : 0;
  int v = orig;
  int lane = threadIdx.x & 63, wave = threadIdx.x >> 6;
#pragma unroll
  for (int off = 1; off < 64; off <<= 1) {
    int u = __shfl_up(v, off);
    if (lane >= off) v += u;
  }
  __shared__ int wsum[4];
  if (lane == 63) wsum[wave] = v;
  __syncthreads();
  int base = 0;
  for (int w = 0; w < wave; w++) base += wsum[w];
  int incl = v + base;
  if (i < N_NODES) excl[i] = incl - orig;
  if (threadIdx.x == 255) bsum[blockIdx.x] = incl;
}

__global__ __launch_bounds__(256) void k_scan2(int* __restrict__ bsum, int nb) {
  int t = threadIdx.x;
  int orig = (t < nb) ? bsum[t] : 0;
  int v = orig;
  int lane = t & 63, wave = t >> 6;
#pragma unroll
  for (int off = 1; off < 64; off <<= 1) {
    int u = __shfl_up(v, off);
    if (lane >= off) v += u;
  }
  __shared__ int wsum[4];
  if (lane == 63) wsum[wave] = v;
  __syncthreads();
  int base = 0;
  for (int w = 0; w < wave; w++) base += wsum[w];
  if (t < nb) bsum[t] = v + base - orig;
}

__global__ __launch_bounds__(256) void k_scan3(const int* __restrict__ excl,
                                               const int* __restrict__ bsum,
                                               int* __restrict__ row_start,
                                               int* __restrict__ cursor) {
  int i = blockIdx.x * 256 + threadIdx.x;
  if (i < N_NODES) {
    int rs = excl[i] + bsum[blockIdx.x];
    row_start[i] = rs;
    cursor[i] = rs;
  }
}

// ---- Kernel 3: counting-sort scatter of minimal 8B records (src, ew) ----
__global__ __launch_bounds__(256) void k_scatter(const int* __restrict__ src,
                                                 const int* __restrict__ dst,
                                                 const float* __restrict__ ew,
                                                 int* __restrict__ cursor,
                                                 int2* __restrict__ rec) {
  int e = blockIdx.x * 256 + threadIdx.x;
  int s = src[e], d = dst[e];
  float w = ew[e];
  int pos = atomicAdd(cursor + d, 1);
  rec[pos] = make_int2(s, __float_as_int(w));
}

// ---- Kernel 4: atomic-free aggregation with in-place softmax recompute ----
// One node per block; wave w = head w. Per edge: recompute
// alpha_un = exp(leaky(as[s]+ad[d])*w - gmax); accumulate denom + message.
__global__ __launch_bounds__(256) void k_agg(const int* __restrict__ row_start,
                                             const int* __restrict__ deg,
                                             const int2* __restrict__ rec,
                                             const float* __restrict__ as,
                                             const float* __restrict__ ad,
                                             const unsigned* __restrict__ gmax,
                                             const float* __restrict__ h,
                                             float* __restrict__ out) {
  __shared__ int ss[64];
  __shared__ float sw[64];
  int d = blockIdx.x;
  int t = threadIdx.x;
  int hd = t >> 6;
  int rs = row_start[d];
  int dg = deg[d];
  float gm = decf(*gmax);
  float ad_d = ad[hd * N_NODES + d];
  float accv = 0.f;
  float den = 0.f;
  for (int j0 = 0; j0 < dg; j0 += 64) {
    int nj = min(64, dg - j0);
    if (t < nj) {
      int2 r = rec[rs + j0 + t];
      ss[t] = r.x;
      sw[t] = __int_as_float(r.y);
    }
    __syncthreads();
    int j = 0;
    for (; j + 1 < nj; j += 2) {
      int s0 = ss[j], s1 = ss[j + 1];
      float w0 = sw[j], w1 = sw[j + 1];
      float v0 = as[hd * N_NODES + s0] + ad_d;
      float v1 = as[hd * N_NODES + s1] + ad_d;
      float h0 = h[(size_t)s0 * HF + t];
      float h1 = h[(size_t)s1 * HF + t];
      v0 = v0 >= 0.f ? v0 : NEG_SLOPE * v0;
      v1 = v1 >= 0.f ? v1 : NEG_SLOPE * v1;
      float al0 = __expf(v0 * w0 - gm);
      float al1 = __expf(v1 * w1 - gm);
      den += al0 + al1;
      accv += al0 * h0 + al1 * h1;
    }
    if (j < nj) {
      int s0 = ss[j];
      float w0 = sw[j];
      float v0 = as[hd * N_NODES + s0] + ad_d;
      v0 = v0 >= 0.f ? v0 : NEG_SLOPE * v0;
      float al0 = __expf(v0 * w0 - gm);
      den += al0;
      accv += al0 * h[(size_t)s0 * HF + t];
    }
    __syncthreads();
  }
  out[(size_t)d * HF + t] = accv / (den + 1e-10f);
}

extern "C" void kernel_launch(void* const* d_in, const int* in_sizes, int n_in,
                              void* d_out, int out_size, void* d_ws, size_t ws_size,
                              hipStream_t stream) {
  const float* x     = (const float*)d_in[0];
  const int*   ei    = (const int*)d_in[1];
  const float* ew    = (const float*)d_in[2];
  const float* W     = (const float*)d_in[3];
  const float* a_src = (const float*)d_in[4];
  const float* a_dst = (const float*)d_in[5];
  float* out = (float*)d_out;

  // workspace layout: h | as | ad | deg | excl | row_start | cursor | rec | bsum | gmax
  float* h  = (float*)d_ws;                          // 12.8M f
  float* as = h + (size_t)N_NODES * HF;              // 200K f
  float* ad = as + (size_t)HEADS * N_NODES;          // 200K f
  int* deg       = (int*)(ad + (size_t)HEADS * N_NODES);
  int* excl      = deg + N_NODES;
  int* row_start = excl + N_NODES;
  int* cursor    = row_start + N_NODES;
  int2* rec      = (int2*)(cursor + N_NODES);        // 800K int2 (8B-aligned: even offset)
  int* bsum      = (int*)(rec + N_EDGES);
  unsigned* gmax = (unsigned*)(bsum + 256);

  const int* src = ei;
  const int* dst = ei + N_EDGES;
  const int NB = (N_NODES + 255) / 256;  // 196

  hipMemsetAsync(deg, 0, (size_t)N_NODES * sizeof(int), stream);
  hipMemsetAsync(gmax, 0, sizeof(unsigned), stream);

  dim3 g1((N_NODES + 63) / 64, HEADS);
  k_gemm<<<g1, 256, 0, stream>>>(x, W, a_src, a_dst, h, as, ad);
  k_edge_max<<<N_EDGES / 256, 256, 0, stream>>>(src, dst, ew, as, ad, gmax, deg);
  k_scan1<<<NB, 256, 0, stream>>>(deg, excl, bsum);
  k_scan2<<<1, 256, 0, stream>>>(bsum, NB);
  k_scan3<<<NB, 256, 0, stream>>>(excl, bsum, row_start, cursor);
  k_scatter<<<N_EDGES / 256, 256, 0, stream>>>(src, dst, ew, cursor, rec);
  k_agg<<<N_NODES, 256, 0, stream>>>(row_start, deg, rec, as, ad, gmax, h, out);
}